// Round 1
// baseline (769.666 us; speedup 1.0000x reference)
//
#include <hip/hip_runtime.h>

// StackedGIN: L=3 layers of { agg = h + scatter_sum(h[src] -> dst);
//   h = relu( relu(agg@W1+B1) @ W2 + B2 ) }, then out = h@Wc + Bc.
// N=50000, E=800000, D=96, C=10.
//
// Strategy: build CSR (counting sort by dst) once per call, then per layer:
//   agg_kernel: pure gather, thread-per-(node,feature), no float atomics
//   mlp_kernel: fused 2-stage GEMM, W staged in LDS (reused buffer), register
//               tile 2 rows x 6 cols per thread.
// ws layout: bufA(N*96 f32) | bufB(N*96 f32) | rowptr(N+1) | cursor(N) |
//            deg(N) | csr(E)   -> ~42.2 MB

#define TPB 256
#define MLP_ROWS 32

__global__ __launch_bounds__(TPB) void hist_kernel(const int* __restrict__ dst,
                                                   int* __restrict__ deg, int E) {
  int e = blockIdx.x * TPB + threadIdx.x;
  if (e < E) atomicAdd(&deg[dst[e]], 1);
}

__global__ __launch_bounds__(1024) void scan_kernel(const int* __restrict__ deg,
                                                    int* __restrict__ rowptr,
                                                    int* __restrict__ cursor, int n) {
  __shared__ int part[1024];
  const int tid = threadIdx.x;
  const int CH = (n + 1023) / 1024;
  int lo = tid * CH;
  int hi = lo + CH; if (hi > n) hi = n;
  int s = 0;
  for (int i = lo; i < hi; i++) s += deg[i];
  part[tid] = s;
  __syncthreads();
  for (int off = 1; off < 1024; off <<= 1) {
    int v = (tid >= off) ? part[tid - off] : 0;
    __syncthreads();
    part[tid] += v;
    __syncthreads();
  }
  int run = (tid == 0) ? 0 : part[tid - 1];
  for (int i = lo; i < hi; i++) {
    rowptr[i] = run;
    cursor[i] = run;
    run += deg[i];
  }
  if (tid == 0) rowptr[n] = part[1023];
}

__global__ __launch_bounds__(TPB) void fill_kernel(const int* __restrict__ src,
                                                   const int* __restrict__ dst,
                                                   int* __restrict__ cursor,
                                                   int* __restrict__ csr, int E) {
  int e = blockIdx.x * TPB + threadIdx.x;
  if (e < E) {
    int d = dst[e];
    int slot = atomicAdd(&cursor[d], 1);
    csr[slot] = src[e];
  }
}

// agg[i][f] = hin[i][f] + sum_{j in row i} hin[csr[j]][f]
__global__ __launch_bounds__(TPB) void agg_kernel(const float* __restrict__ hin,
                                                  float* __restrict__ hout,
                                                  const int* __restrict__ rowptr,
                                                  const int* __restrict__ csr, int n) {
  int t = blockIdx.x * TPB + threadIdx.x;
  if (t >= n * 96) return;
  int i = t / 96;
  int f = t - i * 96;
  float acc = hin[t];
  int s = rowptr[i], e = rowptr[i + 1];
  for (int j = s; j < e; j++) acc += hin[csr[j] * 96 + f];
  hout[t] = acc;
}

// out = relu( relu(in@W1+B1) @ W2 + B2 ), per-block tile of MLP_ROWS rows.
__global__ __launch_bounds__(TPB) void mlp_kernel(const float* __restrict__ in,
                                                  const float* __restrict__ W1,
                                                  const float* __restrict__ B1,
                                                  const float* __restrict__ W2,
                                                  const float* __restrict__ B2,
                                                  float* __restrict__ out, int nrows) {
  __shared__ float Wb[96 * 96];              // 36.9 KB, reused for W1 then W2
  __shared__ float Ta[96][MLP_ROWS + 1];     // input tile, transposed [k][r]
  __shared__ float Tb[96][MLP_ROWS + 1];     // mid tile, transposed
  const int tid = threadIdx.x;
  const int row0 = blockIdx.x * MLP_ROWS;

  for (int idx = tid; idx < MLP_ROWS * 96; idx += TPB) {
    int r = idx / 96, k = idx - (idx / 96) * 96;
    int gr = row0 + r;
    Ta[k][r] = (gr < nrows) ? in[(size_t)gr * 96 + k] : 0.f;
  }
  for (int idx = tid; idx < 96 * 96; idx += TPB) Wb[idx] = W1[idx];
  __syncthreads();

  const int c0 = (tid & 15) * 6;   // 16 col-groups x 6 cols = 96
  const int r0 = (tid >> 4) * 2;   // 16 row-groups x 2 rows = 32
  float acc0[6], acc1[6];
#pragma unroll
  for (int j = 0; j < 6; j++) { acc0[j] = 0.f; acc1[j] = 0.f; }
  for (int k = 0; k < 96; k++) {
    float a0 = Ta[k][r0], a1 = Ta[k][r0 + 1];
#pragma unroll
    for (int j = 0; j < 6; j++) {
      float w = Wb[k * 96 + c0 + j];
      acc0[j] += a0 * w;
      acc1[j] += a1 * w;
    }
  }
#pragma unroll
  for (int j = 0; j < 6; j++) {
    float b = B1[c0 + j];
    Tb[c0 + j][r0]     = fmaxf(acc0[j] + b, 0.f);
    Tb[c0 + j][r0 + 1] = fmaxf(acc1[j] + b, 0.f);
  }
  __syncthreads();  // stage-1 Wb reads done in all threads; Tb complete
  for (int idx = tid; idx < 96 * 96; idx += TPB) Wb[idx] = W2[idx];
  __syncthreads();

#pragma unroll
  for (int j = 0; j < 6; j++) { acc0[j] = 0.f; acc1[j] = 0.f; }
  for (int k = 0; k < 96; k++) {
    float a0 = Tb[k][r0], a1 = Tb[k][r0 + 1];
#pragma unroll
    for (int j = 0; j < 6; j++) {
      float w = Wb[k * 96 + c0 + j];
      acc0[j] += a0 * w;
      acc1[j] += a1 * w;
    }
  }
  int gr0 = row0 + r0;
#pragma unroll
  for (int j = 0; j < 6; j++) {
    float b = B2[c0 + j];
    if (gr0 < nrows)     out[(size_t)gr0 * 96 + c0 + j]       = fmaxf(acc0[j] + b, 0.f);
    if (gr0 + 1 < nrows) out[(size_t)(gr0 + 1) * 96 + c0 + j] = fmaxf(acc1[j] + b, 0.f);
  }
}

// out[i][c] = Bc[c] + sum_k h[i][k] * Wc[k][c]
__global__ __launch_bounds__(TPB) void cls_kernel(const float* __restrict__ h,
                                                  const float* __restrict__ Wc,
                                                  const float* __restrict__ Bc,
                                                  float* __restrict__ out, int n) {
  int t = blockIdx.x * TPB + threadIdx.x;
  if (t >= n * 10) return;
  int i = t / 10;
  int c = t - i * 10;
  float acc = Bc[c];
  const float* hr = h + (size_t)i * 96;
  for (int k = 0; k < 96; k++) acc += hr[k] * Wc[k * 10 + c];
  out[t] = acc;
}

extern "C" void kernel_launch(void* const* d_in, const int* in_sizes, int n_in,
                              void* d_out, int out_size, void* d_ws, size_t ws_size,
                              hipStream_t stream) {
  const float* x  = (const float*)d_in[0];
  const int*   ei = (const int*)d_in[1];
  const float* W1 = (const float*)d_in[2];
  const float* B1 = (const float*)d_in[3];
  const float* W2 = (const float*)d_in[4];
  const float* B2 = (const float*)d_in[5];
  const float* Wc = (const float*)d_in[6];
  const float* Bc = (const float*)d_in[7];
  float* out = (float*)d_out;

  const int N = in_sizes[0] / 96;
  const int E = in_sizes[1] / 2;
  const int* src = ei;       // edge_index[0]
  const int* dst = ei + E;   // edge_index[1]

  float* bufA = (float*)d_ws;
  float* bufB = bufA + (size_t)N * 96;
  int* rowptr = (int*)(bufB + (size_t)N * 96);
  int* cursor = rowptr + (N + 1);
  int* deg    = cursor + N;
  int* csr    = deg + N;

  hipMemsetAsync(deg, 0, (size_t)N * sizeof(int), stream);
  hist_kernel<<<(E + TPB - 1) / TPB, TPB, 0, stream>>>(dst, deg, E);
  scan_kernel<<<1, 1024, 0, stream>>>(deg, rowptr, cursor, N);
  fill_kernel<<<(E + TPB - 1) / TPB, TPB, 0, stream>>>(src, dst, cursor, csr, E);

  const float* hin = x;
  for (int l = 0; l < 3; l++) {
    agg_kernel<<<((N * 96) + TPB - 1) / TPB, TPB, 0, stream>>>(hin, bufB, rowptr, csr, N);
    mlp_kernel<<<(N + MLP_ROWS - 1) / MLP_ROWS, TPB, 0, stream>>>(
        bufB, W1 + (size_t)l * 9216, B1 + (size_t)l * 96,
        W2 + (size_t)l * 9216, B2 + (size_t)l * 96, bufA, N);
    hin = bufA;
  }
  cls_kernel<<<((N * 10) + TPB - 1) / TPB, TPB, 0, stream>>>(bufA, Wc, Bc, out, N);
}

// Round 2
// 555.982 us; speedup vs baseline: 1.3843x; 1.3843x over previous
//
#include <hip/hip_runtime.h>

// StackedGIN: L=3 layers of { agg = h + scatter_sum(h[src] -> dst);
//   h = relu( relu(agg@W1+B1) @ W2 + B2 ) }, then out = h@Wc + Bc.
// N=50000, E=800000, D=96, C=10.
//
// R1: agg rewritten as float4 gather (24 threads/node) with neighbor loop
//     unrolled x4 -> 4 independent 16B gathers in flight per lane (MLP fix;
//     R0 profile showed 8-VGPR latency-bound gather: VALUBusy 15%, HBM 16%).
// ws layout: bufA(N*96 f32) | bufB(N*96 f32) | rowptr(N+1) | cursor(N) |
//            deg(N) | csr(E)

#define TPB 256
#define MLP_ROWS 32

__global__ __launch_bounds__(TPB) void hist_kernel(const int* __restrict__ dst,
                                                   int* __restrict__ deg, int E) {
  int e = blockIdx.x * TPB + threadIdx.x;
  if (e < E) atomicAdd(&deg[dst[e]], 1);
}

__global__ __launch_bounds__(1024) void scan_kernel(const int* __restrict__ deg,
                                                    int* __restrict__ rowptr,
                                                    int* __restrict__ cursor, int n) {
  __shared__ int part[1024];
  const int tid = threadIdx.x;
  const int CH = (n + 1023) / 1024;
  int lo = tid * CH;
  int hi = lo + CH; if (hi > n) hi = n;
  int s = 0;
  for (int i = lo; i < hi; i++) s += deg[i];
  part[tid] = s;
  __syncthreads();
  for (int off = 1; off < 1024; off <<= 1) {
    int v = (tid >= off) ? part[tid - off] : 0;
    __syncthreads();
    part[tid] += v;
    __syncthreads();
  }
  int run = (tid == 0) ? 0 : part[tid - 1];
  for (int i = lo; i < hi; i++) {
    rowptr[i] = run;
    cursor[i] = run;
    run += deg[i];
  }
  if (tid == 0) rowptr[n] = part[1023];
}

__global__ __launch_bounds__(TPB) void fill_kernel(const int* __restrict__ src,
                                                   const int* __restrict__ dst,
                                                   int* __restrict__ cursor,
                                                   int* __restrict__ csr, int E) {
  int e = blockIdx.x * TPB + threadIdx.x;
  if (e < E) {
    int d = dst[e];
    int slot = atomicAdd(&cursor[d], 1);
    csr[slot] = src[e];
  }
}

// agg[i][f4] = hin[i][f4] + sum_{j in row i} hin[csr[j]][f4], float4 lanes.
// 24 threads per node (96/4), neighbor loop unrolled x4 for MLP.
__global__ __launch_bounds__(TPB) void agg4_kernel(const float4* __restrict__ hin4,
                                                   float4* __restrict__ hout4,
                                                   const int* __restrict__ rowptr,
                                                   const int* __restrict__ csr, int n) {
  int t = blockIdx.x * TPB + threadIdx.x;
  if (t >= n * 24) return;
  int i = t / 24;
  int f = t - i * 24;
  float4 acc = hin4[t];
  int s = rowptr[i], e = rowptr[i + 1];
  int j = s;
  for (; j + 4 <= e; j += 4) {
    int i0 = csr[j], i1 = csr[j + 1], i2 = csr[j + 2], i3 = csr[j + 3];
    float4 v0 = hin4[(size_t)i0 * 24 + f];
    float4 v1 = hin4[(size_t)i1 * 24 + f];
    float4 v2 = hin4[(size_t)i2 * 24 + f];
    float4 v3 = hin4[(size_t)i3 * 24 + f];
    acc.x += (v0.x + v1.x) + (v2.x + v3.x);
    acc.y += (v0.y + v1.y) + (v2.y + v3.y);
    acc.z += (v0.z + v1.z) + (v2.z + v3.z);
    acc.w += (v0.w + v1.w) + (v2.w + v3.w);
  }
  for (; j < e; j++) {
    float4 v = hin4[(size_t)csr[j] * 24 + f];
    acc.x += v.x; acc.y += v.y; acc.z += v.z; acc.w += v.w;
  }
  hout4[t] = acc;
}

// out = relu( relu(in@W1+B1) @ W2 + B2 ), per-block tile of MLP_ROWS rows.
__global__ __launch_bounds__(TPB) void mlp_kernel(const float* __restrict__ in,
                                                  const float* __restrict__ W1,
                                                  const float* __restrict__ B1,
                                                  const float* __restrict__ W2,
                                                  const float* __restrict__ B2,
                                                  float* __restrict__ out, int nrows) {
  __shared__ float Wb[96 * 96];              // 36.9 KB, reused for W1 then W2
  __shared__ float Ta[96][MLP_ROWS + 1];     // input tile, transposed [k][r]
  __shared__ float Tb[96][MLP_ROWS + 1];     // mid tile, transposed
  const int tid = threadIdx.x;
  const int row0 = blockIdx.x * MLP_ROWS;

  for (int idx = tid; idx < MLP_ROWS * 96; idx += TPB) {
    int r = idx / 96, k = idx - (idx / 96) * 96;
    int gr = row0 + r;
    Ta[k][r] = (gr < nrows) ? in[(size_t)gr * 96 + k] : 0.f;
  }
  for (int idx = tid; idx < 96 * 96; idx += TPB) Wb[idx] = W1[idx];
  __syncthreads();

  const int c0 = (tid & 15) * 6;   // 16 col-groups x 6 cols = 96
  const int r0 = (tid >> 4) * 2;   // 16 row-groups x 2 rows = 32
  float acc0[6], acc1[6];
#pragma unroll
  for (int j = 0; j < 6; j++) { acc0[j] = 0.f; acc1[j] = 0.f; }
  for (int k = 0; k < 96; k++) {
    float a0 = Ta[k][r0], a1 = Ta[k][r0 + 1];
#pragma unroll
    for (int j = 0; j < 6; j++) {
      float w = Wb[k * 96 + c0 + j];
      acc0[j] += a0 * w;
      acc1[j] += a1 * w;
    }
  }
#pragma unroll
  for (int j = 0; j < 6; j++) {
    float b = B1[c0 + j];
    Tb[c0 + j][r0]     = fmaxf(acc0[j] + b, 0.f);
    Tb[c0 + j][r0 + 1] = fmaxf(acc1[j] + b, 0.f);
  }
  __syncthreads();  // stage-1 Wb reads done in all threads; Tb complete
  for (int idx = tid; idx < 96 * 96; idx += TPB) Wb[idx] = W2[idx];
  __syncthreads();

#pragma unroll
  for (int j = 0; j < 6; j++) { acc0[j] = 0.f; acc1[j] = 0.f; }
  for (int k = 0; k < 96; k++) {
    float a0 = Tb[k][r0], a1 = Tb[k][r0 + 1];
#pragma unroll
    for (int j = 0; j < 6; j++) {
      float w = Wb[k * 96 + c0 + j];
      acc0[j] += a0 * w;
      acc1[j] += a1 * w;
    }
  }
  int gr0 = row0 + r0;
#pragma unroll
  for (int j = 0; j < 6; j++) {
    float b = B2[c0 + j];
    if (gr0 < nrows)     out[(size_t)gr0 * 96 + c0 + j]       = fmaxf(acc0[j] + b, 0.f);
    if (gr0 + 1 < nrows) out[(size_t)(gr0 + 1) * 96 + c0 + j] = fmaxf(acc1[j] + b, 0.f);
  }
}

// out[i][c] = Bc[c] + sum_k h[i][k] * Wc[k][c]
__global__ __launch_bounds__(TPB) void cls_kernel(const float* __restrict__ h,
                                                  const float* __restrict__ Wc,
                                                  const float* __restrict__ Bc,
                                                  float* __restrict__ out, int n) {
  int t = blockIdx.x * TPB + threadIdx.x;
  if (t >= n * 10) return;
  int i = t / 10;
  int c = t - i * 10;
  float acc = Bc[c];
  const float* hr = h + (size_t)i * 96;
  for (int k = 0; k < 96; k++) acc += hr[k] * Wc[k * 10 + c];
  out[t] = acc;
}

extern "C" void kernel_launch(void* const* d_in, const int* in_sizes, int n_in,
                              void* d_out, int out_size, void* d_ws, size_t ws_size,
                              hipStream_t stream) {
  const float* x  = (const float*)d_in[0];
  const int*   ei = (const int*)d_in[1];
  const float* W1 = (const float*)d_in[2];
  const float* B1 = (const float*)d_in[3];
  const float* W2 = (const float*)d_in[4];
  const float* B2 = (const float*)d_in[5];
  const float* Wc = (const float*)d_in[6];
  const float* Bc = (const float*)d_in[7];
  float* out = (float*)d_out;

  const int N = in_sizes[0] / 96;
  const int E = in_sizes[1] / 2;
  const int* src = ei;       // edge_index[0]
  const int* dst = ei + E;   // edge_index[1]

  float* bufA = (float*)d_ws;
  float* bufB = bufA + (size_t)N * 96;
  int* rowptr = (int*)(bufB + (size_t)N * 96);
  int* cursor = rowptr + (N + 1);
  int* deg    = cursor + N;
  int* csr    = deg + N;

  hipMemsetAsync(deg, 0, (size_t)N * sizeof(int), stream);
  hist_kernel<<<(E + TPB - 1) / TPB, TPB, 0, stream>>>(dst, deg, E);
  scan_kernel<<<1, 1024, 0, stream>>>(deg, rowptr, cursor, N);
  fill_kernel<<<(E + TPB - 1) / TPB, TPB, 0, stream>>>(src, dst, cursor, csr, E);

  const float* hin = x;
  for (int l = 0; l < 3; l++) {
    agg4_kernel<<<((N * 24) + TPB - 1) / TPB, TPB, 0, stream>>>(
        (const float4*)hin, (float4*)bufB, rowptr, csr, N);
    mlp_kernel<<<(N + MLP_ROWS - 1) / MLP_ROWS, TPB, 0, stream>>>(
        bufB, W1 + (size_t)l * 9216, B1 + (size_t)l * 96,
        W2 + (size_t)l * 9216, B2 + (size_t)l * 96, bufA, N);
    hin = bufA;
  }
  cls_kernel<<<((N * 10) + TPB - 1) / TPB, TPB, 0, stream>>>(bufA, Wc, Bc, out, N);
}

// Round 3
// 457.527 us; speedup vs baseline: 1.6822x; 1.2152x over previous
//
#include <hip/hip_runtime.h>

// StackedGIN: L=3 layers of { agg = h + scatter_sum(h[src] -> dst);
//   h = relu( relu(agg@W1+B1) @ W2 + B2 ) }, then out = h@Wc + Bc.
// N=50000, E=800000, D=96, C=10.
//
// R1: agg = float4 gather (24 threads/node), neighbor loop unrolled x4.
// R2: replaced single-block serial scan (110us, #1 in profile) with
//     wave-scan + 1 atomicAdd per wave on a global counter (~3us).
//     Slot ranges need not be node-ordered: agg reads [start[i], start[i]+deg[i]).
// ws layout: bufA(N*96 f32) | bufB(N*96 f32) | start(N) | cursor(N) |
//            deg(N) | counter(1) | csr(E)

#define TPB 256
#define MLP_ROWS 32

__global__ __launch_bounds__(TPB) void hist_kernel(const int* __restrict__ dst,
                                                   int* __restrict__ deg, int E) {
  int e = blockIdx.x * TPB + threadIdx.x;
  if (e < E) atomicAdd(&deg[dst[e]], 1);
}

// start[i] = running sum of deg in wave-chunked order (order irrelevant).
__global__ __launch_bounds__(TPB) void assign_kernel(const int* __restrict__ deg,
                                                     int* __restrict__ start,
                                                     int* __restrict__ cursor,
                                                     int* __restrict__ counter, int n) {
  int i = blockIdx.x * TPB + threadIdx.x;
  int d = (i < n) ? deg[i] : 0;
  int lane = threadIdx.x & 63;
  int incl = d;
#pragma unroll
  for (int off = 1; off < 64; off <<= 1) {
    int v = __shfl_up(incl, off, 64);
    if (lane >= off) incl += v;
  }
  int waveTotal = __shfl(incl, 63, 64);
  int base = 0;
  if (lane == 63) base = atomicAdd(counter, waveTotal);
  base = __shfl(base, 63, 64);
  int st = base + incl - d;
  if (i < n) { start[i] = st; cursor[i] = st; }
}

__global__ __launch_bounds__(TPB) void fill_kernel(const int* __restrict__ src,
                                                   const int* __restrict__ dst,
                                                   int* __restrict__ cursor,
                                                   int* __restrict__ csr, int E) {
  int e = blockIdx.x * TPB + threadIdx.x;
  if (e < E) {
    int d = dst[e];
    int slot = atomicAdd(&cursor[d], 1);
    csr[slot] = src[e];
  }
}

// agg[i][f4] = hin[i][f4] + sum_{j in row i} hin[csr[j]][f4], float4 lanes.
// 24 threads per node (96/4), neighbor loop unrolled x4 for MLP.
__global__ __launch_bounds__(TPB) void agg4_kernel(const float4* __restrict__ hin4,
                                                   float4* __restrict__ hout4,
                                                   const int* __restrict__ start,
                                                   const int* __restrict__ deg,
                                                   const int* __restrict__ csr, int n) {
  int t = blockIdx.x * TPB + threadIdx.x;
  if (t >= n * 24) return;
  int i = t / 24;
  int f = t - i * 24;
  float4 acc = hin4[t];
  int s = start[i], e = s + deg[i];
  int j = s;
  for (; j + 4 <= e; j += 4) {
    int i0 = csr[j], i1 = csr[j + 1], i2 = csr[j + 2], i3 = csr[j + 3];
    float4 v0 = hin4[(size_t)i0 * 24 + f];
    float4 v1 = hin4[(size_t)i1 * 24 + f];
    float4 v2 = hin4[(size_t)i2 * 24 + f];
    float4 v3 = hin4[(size_t)i3 * 24 + f];
    acc.x += (v0.x + v1.x) + (v2.x + v3.x);
    acc.y += (v0.y + v1.y) + (v2.y + v3.y);
    acc.z += (v0.z + v1.z) + (v2.z + v3.z);
    acc.w += (v0.w + v1.w) + (v2.w + v3.w);
  }
  for (; j < e; j++) {
    float4 v = hin4[(size_t)csr[j] * 24 + f];
    acc.x += v.x; acc.y += v.y; acc.z += v.z; acc.w += v.w;
  }
  hout4[t] = acc;
}

// out = relu( relu(in@W1+B1) @ W2 + B2 ), per-block tile of MLP_ROWS rows.
__global__ __launch_bounds__(TPB) void mlp_kernel(const float* __restrict__ in,
                                                  const float* __restrict__ W1,
                                                  const float* __restrict__ B1,
                                                  const float* __restrict__ W2,
                                                  const float* __restrict__ B2,
                                                  float* __restrict__ out, int nrows) {
  __shared__ float Wb[96 * 96];              // 36.9 KB, reused for W1 then W2
  __shared__ float Ta[96][MLP_ROWS + 1];     // input tile, transposed [k][r]
  __shared__ float Tb[96][MLP_ROWS + 1];     // mid tile, transposed
  const int tid = threadIdx.x;
  const int row0 = blockIdx.x * MLP_ROWS;

  for (int idx = tid; idx < MLP_ROWS * 96; idx += TPB) {
    int r = idx / 96, k = idx - (idx / 96) * 96;
    int gr = row0 + r;
    Ta[k][r] = (gr < nrows) ? in[(size_t)gr * 96 + k] : 0.f;
  }
  for (int idx = tid; idx < 96 * 96; idx += TPB) Wb[idx] = W1[idx];
  __syncthreads();

  const int c0 = (tid & 15) * 6;   // 16 col-groups x 6 cols = 96
  const int r0 = (tid >> 4) * 2;   // 16 row-groups x 2 rows = 32
  float acc0[6], acc1[6];
#pragma unroll
  for (int j = 0; j < 6; j++) { acc0[j] = 0.f; acc1[j] = 0.f; }
  for (int k = 0; k < 96; k++) {
    float a0 = Ta[k][r0], a1 = Ta[k][r0 + 1];
#pragma unroll
    for (int j = 0; j < 6; j++) {
      float w = Wb[k * 96 + c0 + j];
      acc0[j] += a0 * w;
      acc1[j] += a1 * w;
    }
  }
#pragma unroll
  for (int j = 0; j < 6; j++) {
    float b = B1[c0 + j];
    Tb[c0 + j][r0]     = fmaxf(acc0[j] + b, 0.f);
    Tb[c0 + j][r0 + 1] = fmaxf(acc1[j] + b, 0.f);
  }
  __syncthreads();  // stage-1 Wb reads done in all threads; Tb complete
  for (int idx = tid; idx < 96 * 96; idx += TPB) Wb[idx] = W2[idx];
  __syncthreads();

#pragma unroll
  for (int j = 0; j < 6; j++) { acc0[j] = 0.f; acc1[j] = 0.f; }
  for (int k = 0; k < 96; k++) {
    float a0 = Tb[k][r0], a1 = Tb[k][r0 + 1];
#pragma unroll
    for (int j = 0; j < 6; j++) {
      float w = Wb[k * 96 + c0 + j];
      acc0[j] += a0 * w;
      acc1[j] += a1 * w;
    }
  }
  int gr0 = row0 + r0;
#pragma unroll
  for (int j = 0; j < 6; j++) {
    float b = B2[c0 + j];
    if (gr0 < nrows)     out[(size_t)gr0 * 96 + c0 + j]       = fmaxf(acc0[j] + b, 0.f);
    if (gr0 + 1 < nrows) out[(size_t)(gr0 + 1) * 96 + c0 + j] = fmaxf(acc1[j] + b, 0.f);
  }
}

// out[i][c] = Bc[c] + sum_k h[i][k] * Wc[k][c]
__global__ __launch_bounds__(TPB) void cls_kernel(const float* __restrict__ h,
                                                  const float* __restrict__ Wc,
                                                  const float* __restrict__ Bc,
                                                  float* __restrict__ out, int n) {
  int t = blockIdx.x * TPB + threadIdx.x;
  if (t >= n * 10) return;
  int i = t / 10;
  int c = t - i * 10;
  float acc = Bc[c];
  const float* hr = h + (size_t)i * 96;
  for (int k = 0; k < 96; k++) acc += hr[k] * Wc[k * 10 + c];
  out[t] = acc;
}

extern "C" void kernel_launch(void* const* d_in, const int* in_sizes, int n_in,
                              void* d_out, int out_size, void* d_ws, size_t ws_size,
                              hipStream_t stream) {
  const float* x  = (const float*)d_in[0];
  const int*   ei = (const int*)d_in[1];
  const float* W1 = (const float*)d_in[2];
  const float* B1 = (const float*)d_in[3];
  const float* W2 = (const float*)d_in[4];
  const float* B2 = (const float*)d_in[5];
  const float* Wc = (const float*)d_in[6];
  const float* Bc = (const float*)d_in[7];
  float* out = (float*)d_out;

  const int N = in_sizes[0] / 96;
  const int E = in_sizes[1] / 2;
  const int* src = ei;       // edge_index[0]
  const int* dst = ei + E;   // edge_index[1]

  float* bufA = (float*)d_ws;
  float* bufB = bufA + (size_t)N * 96;
  int* start   = (int*)(bufB + (size_t)N * 96);
  int* cursor  = start + N;
  int* deg     = cursor + N;
  int* counter = deg + N;
  int* csr     = counter + 1;

  hipMemsetAsync(deg, 0, (size_t)(N + 1) * sizeof(int), stream);  // deg + counter
  hist_kernel<<<(E + TPB - 1) / TPB, TPB, 0, stream>>>(dst, deg, E);
  assign_kernel<<<(N + TPB - 1) / TPB, TPB, 0, stream>>>(deg, start, cursor, counter, N);
  fill_kernel<<<(E + TPB - 1) / TPB, TPB, 0, stream>>>(src, dst, cursor, csr, E);

  const float* hin = x;
  for (int l = 0; l < 3; l++) {
    agg4_kernel<<<((N * 24) + TPB - 1) / TPB, TPB, 0, stream>>>(
        (const float4*)hin, (float4*)bufB, start, deg, csr, N);
    mlp_kernel<<<(N + MLP_ROWS - 1) / MLP_ROWS, TPB, 0, stream>>>(
        bufB, W1 + (size_t)l * 9216, B1 + (size_t)l * 96,
        W2 + (size_t)l * 9216, B2 + (size_t)l * 96, bufA, N);
    hin = bufA;
  }
  cls_kernel<<<((N * 10) + TPB - 1) / TPB, TPB, 0, stream>>>(bufA, Wc, Bc, out, N);
}

// Round 4
// 330.334 us; speedup vs baseline: 2.3300x; 1.3850x over previous
//
#include <hip/hip_runtime.h>

// StackedGIN: L=3 layers of { agg = h + scatter_sum(h[src] -> dst);
//   h = relu( relu(agg@W1+B1) @ W2 + B2 ) }, then out = h@Wc + Bc.
// N=50000, E=800000, D=96, C=10.
//
// R1: agg = float4 gather (24 threads/node), neighbor loop unrolled x4.
// R2: wave-scan slot assignment (order-free CSR ranges), 1 atomic/wave.
// R3: MLP via bf16 MFMA (mfma_f32_16x16x32_bf16). Weights pre-transposed to
//     bf16 Wt[n][k] once per call (stored in dead cursor region). 64 rows per
//     block, 4 waves x 16-row stripe, LDS stride 104 (+8 pad -> 2-way banks).
//     Z (relu(GEMM1)) overwrites wave-private A stripe in LDS; 1 barrier.
// ws layout: bufA(N*96 f32) | bufB(N*96 f32) | start(N) | cursor(N, reused as
//            bf16 Wt[6][96][96] after fill) | deg(N) | counter(1) | csr(E)

#define TPB 256
#define LDA 104  // bf16 elems per LDS row: 96 + 8 pad

typedef __attribute__((ext_vector_type(8))) short bfrag8;
typedef __attribute__((ext_vector_type(4))) float f32x4;

__device__ inline unsigned short f2bf(float x) {  // RNE f32 -> bf16 bits
  unsigned int u = __float_as_uint(x);
  unsigned int r = u + 0x7FFFu + ((u >> 16) & 1u);
  return (unsigned short)(r >> 16);
}

__global__ __launch_bounds__(TPB) void hist_kernel(const int* __restrict__ dst,
                                                   int* __restrict__ deg, int E) {
  int e = blockIdx.x * TPB + threadIdx.x;
  if (e < E) atomicAdd(&deg[dst[e]], 1);
}

// start[i] = running sum of deg in wave-chunked order (order irrelevant).
__global__ __launch_bounds__(TPB) void assign_kernel(const int* __restrict__ deg,
                                                     int* __restrict__ start,
                                                     int* __restrict__ cursor,
                                                     int* __restrict__ counter, int n) {
  int i = blockIdx.x * TPB + threadIdx.x;
  int d = (i < n) ? deg[i] : 0;
  int lane = threadIdx.x & 63;
  int incl = d;
#pragma unroll
  for (int off = 1; off < 64; off <<= 1) {
    int v = __shfl_up(incl, off, 64);
    if (lane >= off) incl += v;
  }
  int waveTotal = __shfl(incl, 63, 64);
  int base = 0;
  if (lane == 63) base = atomicAdd(counter, waveTotal);
  base = __shfl(base, 63, 64);
  int st = base + incl - d;
  if (i < n) { start[i] = st; cursor[i] = st; }
}

__global__ __launch_bounds__(TPB) void fill_kernel(const int* __restrict__ src,
                                                   const int* __restrict__ dst,
                                                   int* __restrict__ cursor,
                                                   int* __restrict__ csr, int E) {
  int e = blockIdx.x * TPB + threadIdx.x;
  if (e < E) {
    int d = dst[e];
    int slot = atomicAdd(&cursor[d], 1);
    csr[slot] = src[e];
  }
}

// wt[l*2+which][n][k] = bf16(W[l][k][n])  (transposed, bf16)
__global__ __launch_bounds__(TPB) void wprep_kernel(const float* __restrict__ W1,
                                                    const float* __restrict__ W2,
                                                    unsigned short* __restrict__ wt) {
  int t = blockIdx.x * TPB + threadIdx.x;
  if (t >= 6 * 9216) return;
  int mat = t / 9216, idx = t - mat * 9216;
  int l = mat >> 1, which = mat & 1;
  int k = idx / 96, n = idx - k * 96;
  const float* src = (which ? W2 : W1) + (size_t)l * 9216;
  wt[(size_t)mat * 9216 + n * 96 + k] = f2bf(src[k * 96 + n]);
}

// agg[i][f4] = hin[i][f4] + sum_{j in row i} hin[csr[j]][f4], float4 lanes.
__global__ __launch_bounds__(TPB) void agg4_kernel(const float4* __restrict__ hin4,
                                                   float4* __restrict__ hout4,
                                                   const int* __restrict__ start,
                                                   const int* __restrict__ deg,
                                                   const int* __restrict__ csr, int n) {
  int t = blockIdx.x * TPB + threadIdx.x;
  if (t >= n * 24) return;
  int i = t / 24;
  int f = t - i * 24;
  float4 acc = hin4[t];
  int s = start[i], e = s + deg[i];
  int j = s;
  for (; j + 4 <= e; j += 4) {
    int i0 = csr[j], i1 = csr[j + 1], i2 = csr[j + 2], i3 = csr[j + 3];
    float4 v0 = hin4[(size_t)i0 * 24 + f];
    float4 v1 = hin4[(size_t)i1 * 24 + f];
    float4 v2 = hin4[(size_t)i2 * 24 + f];
    float4 v3 = hin4[(size_t)i3 * 24 + f];
    acc.x += (v0.x + v1.x) + (v2.x + v3.x);
    acc.y += (v0.y + v1.y) + (v2.y + v3.y);
    acc.z += (v0.z + v1.z) + (v2.z + v3.z);
    acc.w += (v0.w + v1.w) + (v2.w + v3.w);
  }
  for (; j < e; j++) {
    float4 v = hin4[(size_t)csr[j] * 24 + f];
    acc.x += v.x; acc.y += v.y; acc.z += v.z; acc.w += v.w;
  }
  hout4[t] = acc;
}

// out = relu( relu(in@W1+B1) @ W2 + B2 ) via bf16 MFMA.
// Block: 64 rows, 4 waves x 16-row stripe. Wt1/Wt2 are bf16 [n][k].
__global__ __launch_bounds__(TPB) void mlp_mfma_kernel(
    const float* __restrict__ in, const unsigned short* __restrict__ wt1,
    const unsigned short* __restrict__ wt2, const float* __restrict__ B1,
    const float* __restrict__ B2, float* __restrict__ out, int nrows) {
  __shared__ unsigned short A_lds[64 * LDA];   // A tile, later Z tile
  __shared__ unsigned short W1_lds[96 * LDA];
  __shared__ unsigned short W2_lds[96 * LDA];
  const int tid = threadIdx.x;
  const int row0 = blockIdx.x * 64;

  // stage A: f32 -> bf16, rows [row0, row0+64)
  for (int t = tid; t < 64 * 24; t += TPB) {
    int r = t / 24, c4 = t - r * 24;
    int gr = row0 + r;
    float4 v = make_float4(0.f, 0.f, 0.f, 0.f);
    if (gr < nrows) v = *reinterpret_cast<const float4*>(in + (size_t)gr * 96 + 4 * c4);
    ushort4 b;
    b.x = f2bf(v.x); b.y = f2bf(v.y); b.z = f2bf(v.z); b.w = f2bf(v.w);
    *reinterpret_cast<ushort4*>(&A_lds[r * LDA + 4 * c4]) = b;
  }
  // stage Wt1, Wt2 (bf16, 16B chunks)
  for (int t = tid; t < 2 * 1152; t += TPB) {
    int which = t / 1152, idx = t - which * 1152;
    int n = idx / 12, c8 = idx - n * 12;
    const unsigned short* src = (which ? wt2 : wt1) + n * 96 + 8 * c8;
    bfrag8 v = *reinterpret_cast<const bfrag8*>(src);
    unsigned short* dp = (which ? W2_lds : W1_lds) + n * LDA + 8 * c8;
    *reinterpret_cast<bfrag8*>(dp) = v;
  }
  __syncthreads();

  const int lane = tid & 63;
  const int w = tid >> 6;     // wave id: rows [16w, 16w+16)
  const int nl = lane & 15;   // frag row (A) / col (B,D)
  const int q = lane >> 4;    // k-quarter
  const int arow = 16 * w + nl;

  bfrag8 afrag[3];
#pragma unroll
  for (int s = 0; s < 3; s++)
    afrag[s] = *reinterpret_cast<const bfrag8*>(&A_lds[arow * LDA + 32 * s + 8 * q]);

  // GEMM1 -> relu -> Z (bf16) into this wave's own A stripe (no barrier needed)
#pragma unroll
  for (int cb = 0; cb < 6; cb++) {
    f32x4 acc = {0.f, 0.f, 0.f, 0.f};
#pragma unroll
    for (int s = 0; s < 3; s++) {
      bfrag8 bfr = *reinterpret_cast<const bfrag8*>(
          &W1_lds[(16 * cb + nl) * LDA + 32 * s + 8 * q]);
      acc = __builtin_amdgcn_mfma_f32_16x16x32_bf16(afrag[s], bfr, acc, 0, 0, 0);
    }
    float b = B1[16 * cb + nl];
#pragma unroll
    for (int i = 0; i < 4; i++) {
      int m = 16 * w + 4 * q + i;
      A_lds[m * LDA + 16 * cb + nl] = f2bf(fmaxf(acc[i] + b, 0.f));
    }
  }

  bfrag8 zfrag[3];
#pragma unroll
  for (int s = 0; s < 3; s++)
    zfrag[s] = *reinterpret_cast<const bfrag8*>(&A_lds[arow * LDA + 32 * s + 8 * q]);

#pragma unroll
  for (int cb = 0; cb < 6; cb++) {
    f32x4 acc = {0.f, 0.f, 0.f, 0.f};
#pragma unroll
    for (int s = 0; s < 3; s++) {
      bfrag8 bfr = *reinterpret_cast<const bfrag8*>(
          &W2_lds[(16 * cb + nl) * LDA + 32 * s + 8 * q]);
      acc = __builtin_amdgcn_mfma_f32_16x16x32_bf16(zfrag[s], bfr, acc, 0, 0, 0);
    }
    float b = B2[16 * cb + nl];
#pragma unroll
    for (int i = 0; i < 4; i++) {
      int m = 16 * w + 4 * q + i;
      int gr = row0 + m;
      if (gr < nrows) out[(size_t)gr * 96 + 16 * cb + nl] = fmaxf(acc[i] + b, 0.f);
    }
  }
}

// out[i][c] = Bc[c] + sum_k h[i][k] * Wc[k][c]
__global__ __launch_bounds__(TPB) void cls_kernel(const float* __restrict__ h,
                                                  const float* __restrict__ Wc,
                                                  const float* __restrict__ Bc,
                                                  float* __restrict__ out, int n) {
  int t = blockIdx.x * TPB + threadIdx.x;
  if (t >= n * 10) return;
  int i = t / 10;
  int c = t - i * 10;
  float acc = Bc[c];
  const float* hr = h + (size_t)i * 96;
  for (int k = 0; k < 96; k++) acc += hr[k] * Wc[k * 10 + c];
  out[t] = acc;
}

extern "C" void kernel_launch(void* const* d_in, const int* in_sizes, int n_in,
                              void* d_out, int out_size, void* d_ws, size_t ws_size,
                              hipStream_t stream) {
  const float* x  = (const float*)d_in[0];
  const int*   ei = (const int*)d_in[1];
  const float* W1 = (const float*)d_in[2];
  const float* B1 = (const float*)d_in[3];
  const float* W2 = (const float*)d_in[4];
  const float* B2 = (const float*)d_in[5];
  const float* Wc = (const float*)d_in[6];
  const float* Bc = (const float*)d_in[7];
  float* out = (float*)d_out;

  const int N = in_sizes[0] / 96;
  const int E = in_sizes[1] / 2;
  const int* src = ei;       // edge_index[0]
  const int* dst = ei + E;   // edge_index[1]

  float* bufA = (float*)d_ws;
  float* bufB = bufA + (size_t)N * 96;
  int* start   = (int*)(bufB + (size_t)N * 96);
  int* cursor  = start + N;                 // dead after fill -> reused for wt
  int* deg     = cursor + N;
  int* counter = deg + N;
  int* csr     = counter + 1;
  unsigned short* wt = (unsigned short*)cursor;  // 6*9216 u16 = 110.6 KB <= N*4 B

  hipMemsetAsync(deg, 0, (size_t)(N + 1) * sizeof(int), stream);  // deg + counter
  hist_kernel<<<(E + TPB - 1) / TPB, TPB, 0, stream>>>(dst, deg, E);
  assign_kernel<<<(N + TPB - 1) / TPB, TPB, 0, stream>>>(deg, start, cursor, counter, N);
  fill_kernel<<<(E + TPB - 1) / TPB, TPB, 0, stream>>>(src, dst, cursor, csr, E);
  wprep_kernel<<<(6 * 9216 + TPB - 1) / TPB, TPB, 0, stream>>>(W1, W2, wt);

  const float* hin = x;
  for (int l = 0; l < 3; l++) {
    agg4_kernel<<<((N * 24) + TPB - 1) / TPB, TPB, 0, stream>>>(
        (const float4*)hin, (float4*)bufB, start, deg, csr, N);
    mlp_mfma_kernel<<<(N + 63) / 64, TPB, 0, stream>>>(
        bufB, wt + (size_t)(l * 2) * 9216, wt + (size_t)(l * 2 + 1) * 9216,
        B1 + (size_t)l * 96, B2 + (size_t)l * 96, bufA, N);
    hin = bufA;
  }
  cls_kernel<<<((N * 10) + TPB - 1) / TPB, TPB, 0, stream>>>(bufA, Wc, Bc, out, N);
}

// Round 5
// 278.067 us; speedup vs baseline: 2.7679x; 1.1880x over previous
//
#include <hip/hip_runtime.h>

// StackedGIN: L=3 layers of { agg = h + scatter_sum(h[src] -> dst);
//   h = relu( relu(agg@W1+B1) @ W2 + B2 ) }, then out = h@Wc + Bc.
// N=50000, E=800000, D=96, C=10.
//
// R1: agg = float4 gather, unroll x4.   R2: wave-scan slot assignment.
// R3: MLP via bf16 MFMA (16x16x32), weights pre-transposed bf16.
// R4: h and agg stored as bf16 -> gather volume halved (agg was ~135us
//     aggregate). Rounding h pre-sum ~ equals old round-after-sum error.
// ws layout: hbuf(N*96 bf16) | aggbuf(N*96 bf16) | start(N) | cursor(N,
//            reused as bf16 Wt[6][96][96] after fill) | deg(N) | counter(1) | csr(E)

#define TPB 256
#define LDA 104  // bf16 elems per LDS row: 96 + 8 pad

typedef __attribute__((ext_vector_type(8))) short bfrag8;
typedef __attribute__((ext_vector_type(8))) unsigned short u16x8;
typedef __attribute__((ext_vector_type(4))) float f32x4;

__device__ inline unsigned short f2bf(float x) {  // RNE f32 -> bf16 bits
  unsigned int u = __float_as_uint(x);
  unsigned int r = u + 0x7FFFu + ((u >> 16) & 1u);
  return (unsigned short)(r >> 16);
}
__device__ inline float bf2f(unsigned short u) {
  return __uint_as_float(((unsigned int)u) << 16);
}

__global__ __launch_bounds__(TPB) void hist_kernel(const int* __restrict__ dst,
                                                   int* __restrict__ deg, int E) {
  int e = blockIdx.x * TPB + threadIdx.x;
  if (e < E) atomicAdd(&deg[dst[e]], 1);
}

// start[i] = running sum of deg in wave-chunked order (order irrelevant).
__global__ __launch_bounds__(TPB) void assign_kernel(const int* __restrict__ deg,
                                                     int* __restrict__ start,
                                                     int* __restrict__ cursor,
                                                     int* __restrict__ counter, int n) {
  int i = blockIdx.x * TPB + threadIdx.x;
  int d = (i < n) ? deg[i] : 0;
  int lane = threadIdx.x & 63;
  int incl = d;
#pragma unroll
  for (int off = 1; off < 64; off <<= 1) {
    int v = __shfl_up(incl, off, 64);
    if (lane >= off) incl += v;
  }
  int waveTotal = __shfl(incl, 63, 64);
  int base = 0;
  if (lane == 63) base = atomicAdd(counter, waveTotal);
  base = __shfl(base, 63, 64);
  int st = base + incl - d;
  if (i < n) { start[i] = st; cursor[i] = st; }
}

__global__ __launch_bounds__(TPB) void fill_kernel(const int* __restrict__ src,
                                                   const int* __restrict__ dst,
                                                   int* __restrict__ cursor,
                                                   int* __restrict__ csr, int E) {
  int e = blockIdx.x * TPB + threadIdx.x;
  if (e < E) {
    int d = dst[e];
    int slot = atomicAdd(&cursor[d], 1);
    csr[slot] = src[e];
  }
}

// wt[l*2+which][n][k] = bf16(W[l][k][n])  (transposed, bf16)
__global__ __launch_bounds__(TPB) void wprep_kernel(const float* __restrict__ W1,
                                                    const float* __restrict__ W2,
                                                    unsigned short* __restrict__ wt) {
  int t = blockIdx.x * TPB + threadIdx.x;
  if (t >= 6 * 9216) return;
  int mat = t / 9216, idx = t - mat * 9216;
  int l = mat >> 1, which = mat & 1;
  int k = idx / 96, n = idx - k * 96;
  const float* src = (which ? W2 : W1) + (size_t)l * 9216;
  wt[(size_t)mat * 9216 + n * 96 + k] = f2bf(src[k * 96 + n]);
}

// hbuf = bf16(x), 8 elems/thread
__global__ __launch_bounds__(TPB) void x2h_kernel(const float4* __restrict__ x4,
                                                  u16x8* __restrict__ h8, int total8) {
  int t = blockIdx.x * TPB + threadIdx.x;
  if (t >= total8) return;
  float4 a = x4[2 * t], b = x4[2 * t + 1];
  u16x8 o;
  o[0] = f2bf(a.x); o[1] = f2bf(a.y); o[2] = f2bf(a.z); o[3] = f2bf(a.w);
  o[4] = f2bf(b.x); o[5] = f2bf(b.y); o[6] = f2bf(b.z); o[7] = f2bf(b.w);
  h8[t] = o;
}

// agg[i][c8] = h[i][c8] + sum_{j in row i} h[csr[j]][c8]; bf16 in/out,
// f32 accumulate. 12 threads/node (96/8), unroll x4 for MLP.
__global__ __launch_bounds__(TPB) void aggb_kernel(const u16x8* __restrict__ hin8,
                                                   u16x8* __restrict__ hout8,
                                                   const int* __restrict__ start,
                                                   const int* __restrict__ deg,
                                                   const int* __restrict__ csr, int n) {
  int t = blockIdx.x * TPB + threadIdx.x;
  if (t >= n * 12) return;
  int i = t / 12;
  int f = t - i * 12;
  u16x8 self = hin8[t];
  float acc[8];
#pragma unroll
  for (int k = 0; k < 8; k++) acc[k] = bf2f(self[k]);
  int s = start[i], e = s + deg[i];
  int j = s;
  for (; j + 4 <= e; j += 4) {
    int i0 = csr[j], i1 = csr[j + 1], i2 = csr[j + 2], i3 = csr[j + 3];
    u16x8 v0 = hin8[(size_t)i0 * 12 + f];
    u16x8 v1 = hin8[(size_t)i1 * 12 + f];
    u16x8 v2 = hin8[(size_t)i2 * 12 + f];
    u16x8 v3 = hin8[(size_t)i3 * 12 + f];
#pragma unroll
    for (int k = 0; k < 8; k++)
      acc[k] += (bf2f(v0[k]) + bf2f(v1[k])) + (bf2f(v2[k]) + bf2f(v3[k]));
  }
  for (; j < e; j++) {
    u16x8 v = hin8[(size_t)csr[j] * 12 + f];
#pragma unroll
    for (int k = 0; k < 8; k++) acc[k] += bf2f(v[k]);
  }
  u16x8 o;
#pragma unroll
  for (int k = 0; k < 8; k++) o[k] = f2bf(acc[k]);
  hout8[t] = o;
}

// h = relu( relu(agg@W1+B1) @ W2 + B2 ) via bf16 MFMA; agg,h bf16.
// Block: 64 rows, 4 waves x 16-row stripe. Wt1/Wt2 are bf16 [n][k].
__global__ __launch_bounds__(TPB) void mlp_mfma_kernel(
    const u16x8* __restrict__ in8, const unsigned short* __restrict__ wt1,
    const unsigned short* __restrict__ wt2, const float* __restrict__ B1,
    const float* __restrict__ B2, unsigned short* __restrict__ out, int nrows) {
  __shared__ unsigned short A_lds[64 * LDA];   // A tile, later Z tile
  __shared__ unsigned short W1_lds[96 * LDA];
  __shared__ unsigned short W2_lds[96 * LDA];
  const int tid = threadIdx.x;
  const int row0 = blockIdx.x * 64;

  // stage A (already bf16), rows [row0, row0+64)
  for (int t = tid; t < 64 * 12; t += TPB) {
    int r = t / 12, c8 = t - r * 12;
    int gr = row0 + r;
    u16x8 v = {};
    if (gr < nrows) v = in8[(size_t)gr * 12 + c8];
    *reinterpret_cast<u16x8*>(&A_lds[r * LDA + 8 * c8]) = v;
  }
  // stage Wt1, Wt2 (bf16, 16B chunks)
  for (int t = tid; t < 2 * 1152; t += TPB) {
    int which = t / 1152, idx = t - which * 1152;
    int n = idx / 12, c8 = idx - n * 12;
    const unsigned short* src = (which ? wt2 : wt1) + n * 96 + 8 * c8;
    bfrag8 v = *reinterpret_cast<const bfrag8*>(src);
    unsigned short* dp = (which ? W2_lds : W1_lds) + n * LDA + 8 * c8;
    *reinterpret_cast<bfrag8*>(dp) = v;
  }
  __syncthreads();

  const int lane = tid & 63;
  const int w = tid >> 6;     // wave id: rows [16w, 16w+16)
  const int nl = lane & 15;   // frag row (A) / col (B,D)
  const int q = lane >> 4;    // k-quarter
  const int arow = 16 * w + nl;

  bfrag8 afrag[3];
#pragma unroll
  for (int s = 0; s < 3; s++)
    afrag[s] = *reinterpret_cast<const bfrag8*>(&A_lds[arow * LDA + 32 * s + 8 * q]);

  // GEMM1 -> relu -> Z (bf16) into this wave's own A stripe (no barrier needed)
#pragma unroll
  for (int cb = 0; cb < 6; cb++) {
    f32x4 acc = {0.f, 0.f, 0.f, 0.f};
#pragma unroll
    for (int s = 0; s < 3; s++) {
      bfrag8 bfr = *reinterpret_cast<const bfrag8*>(
          &W1_lds[(16 * cb + nl) * LDA + 32 * s + 8 * q]);
      acc = __builtin_amdgcn_mfma_f32_16x16x32_bf16(afrag[s], bfr, acc, 0, 0, 0);
    }
    float b = B1[16 * cb + nl];
#pragma unroll
    for (int i = 0; i < 4; i++) {
      int m = 16 * w + 4 * q + i;
      A_lds[m * LDA + 16 * cb + nl] = f2bf(fmaxf(acc[i] + b, 0.f));
    }
  }

  bfrag8 zfrag[3];
#pragma unroll
  for (int s = 0; s < 3; s++)
    zfrag[s] = *reinterpret_cast<const bfrag8*>(&A_lds[arow * LDA + 32 * s + 8 * q]);

#pragma unroll
  for (int cb = 0; cb < 6; cb++) {
    f32x4 acc = {0.f, 0.f, 0.f, 0.f};
#pragma unroll
    for (int s = 0; s < 3; s++) {
      bfrag8 bfr = *reinterpret_cast<const bfrag8*>(
          &W2_lds[(16 * cb + nl) * LDA + 32 * s + 8 * q]);
      acc = __builtin_amdgcn_mfma_f32_16x16x32_bf16(zfrag[s], bfr, acc, 0, 0, 0);
    }
    float b = B2[16 * cb + nl];
#pragma unroll
    for (int i = 0; i < 4; i++) {
      int m = 16 * w + 4 * q + i;
      int gr = row0 + m;
      if (gr < nrows)
        out[(size_t)gr * 96 + 16 * cb + nl] = f2bf(fmaxf(acc[i] + b, 0.f));
    }
  }
}

// out[i][c] = Bc[c] + sum_k bf2f(h[i][k]) * Wc[k][c]
__global__ __launch_bounds__(TPB) void cls_kernel(const unsigned short* __restrict__ h,
                                                  const float* __restrict__ Wc,
                                                  const float* __restrict__ Bc,
                                                  float* __restrict__ out, int n) {
  int t = blockIdx.x * TPB + threadIdx.x;
  if (t >= n * 10) return;
  int i = t / 10;
  int c = t - i * 10;
  float acc = Bc[c];
  const unsigned short* hr = h + (size_t)i * 96;
  for (int k = 0; k < 96; k++) acc += bf2f(hr[k]) * Wc[k * 10 + c];
  out[t] = acc;
}

extern "C" void kernel_launch(void* const* d_in, const int* in_sizes, int n_in,
                              void* d_out, int out_size, void* d_ws, size_t ws_size,
                              hipStream_t stream) {
  const float* x  = (const float*)d_in[0];
  const int*   ei = (const int*)d_in[1];
  const float* W1 = (const float*)d_in[2];
  const float* B1 = (const float*)d_in[3];
  const float* W2 = (const float*)d_in[4];
  const float* B2 = (const float*)d_in[5];
  const float* Wc = (const float*)d_in[6];
  const float* Bc = (const float*)d_in[7];
  float* out = (float*)d_out;

  const int N = in_sizes[0] / 96;
  const int E = in_sizes[1] / 2;
  const int* src = ei;       // edge_index[0]
  const int* dst = ei + E;   // edge_index[1]

  unsigned short* hbuf   = (unsigned short*)d_ws;        // N*96 bf16
  unsigned short* aggbuf = hbuf + (size_t)N * 96;        // N*96 bf16
  int* start   = (int*)(aggbuf + (size_t)N * 96);
  int* cursor  = start + N;                 // dead after fill -> reused for wt
  int* deg     = cursor + N;
  int* counter = deg + N;
  int* csr     = counter + 1;
  unsigned short* wt = (unsigned short*)cursor;  // 6*9216 u16 = 110.6 KB <= N*4 B

  hipMemsetAsync(deg, 0, (size_t)(N + 1) * sizeof(int), stream);  // deg + counter
  hist_kernel<<<(E + TPB - 1) / TPB, TPB, 0, stream>>>(dst, deg, E);
  assign_kernel<<<(N + TPB - 1) / TPB, TPB, 0, stream>>>(deg, start, cursor, counter, N);
  fill_kernel<<<(E + TPB - 1) / TPB, TPB, 0, stream>>>(src, dst, cursor, csr, E);
  wprep_kernel<<<(6 * 9216 + TPB - 1) / TPB, TPB, 0, stream>>>(W1, W2, wt);
  x2h_kernel<<<((N * 12) + TPB - 1) / TPB, TPB, 0, stream>>>(
      (const float4*)x, (u16x8*)hbuf, N * 12);

  for (int l = 0; l < 3; l++) {
    aggb_kernel<<<((N * 12) + TPB - 1) / TPB, TPB, 0, stream>>>(
        (const u16x8*)hbuf, (u16x8*)aggbuf, start, deg, csr, N);
    mlp_mfma_kernel<<<(N + 63) / 64, TPB, 0, stream>>>(
        (const u16x8*)aggbuf, wt + (size_t)(l * 2) * 9216,
        wt + (size_t)(l * 2 + 1) * 9216,
        B1 + (size_t)l * 96, B2 + (size_t)l * 96, hbuf, N);
  }
  cls_kernel<<<((N * 10) + TPB - 1) / TPB, TPB, 0, stream>>>(hbuf, Wc, Bc, out, N);
}